// Round 1
// baseline (498.145 us; speedup 1.0000x reference)
//
#include <hip/hip_runtime.h>
#include <hip/hip_bf16.h>
#include <stdint.h>

// R6: t_gemm ~60us each; ~250us fixed harness poison/restore overhead.
// R7 (466.7us verified): 64x128 wave tiles, f16 yws.
// R8: fuse LN into gemm1 epilogue, LN+Linear into gemm2 epilogue.
//   Geometry BM=64 x BN=512 (grid 512), 4 waves, wave tile 64x128 -> per-wave
//   main loop identical to R7 (24 ds_read_b128 : 64 MFMA / k-iter), LDS 74KB
//   -> still 2 blocks/CU (cross-block overlap hides barrier vmcnt drain).
//   Removes ln (20us) + ln2pred (12us) dispatches and ~128MB of Y traffic;
//   costs +384MB of L2-resident B staging (B panel is 1.5MB, L2-fits).

typedef _Float16 f16;
typedef _Float16 f16x8 __attribute__((ext_vector_type(8)));
typedef float f32x4 __attribute__((ext_vector_type(4)));

#define B_    32
#define T_    1024
#define TP_   1026
#define C_    512
#define LMAX_ 4096
#define KDIM  1536

// workspace byte offsets (all 256-aligned; keep R7 layout, yws now unused)
#define XPAD_OFF   0u
#define H1PAD_OFF  33619968u     // 32*1026*512*2
#define W1T_OFF    67239936u
#define W2T_OFF    68812800u
#define TOT_OFF    137494528u
#define IDX_OFF    137495040u

#define AS1C(p) ((const __attribute__((address_space(1))) void*)(p))
#define AS3(p)  ((__attribute__((address_space(3))) void*)(p))

// ---------------------------------------------------------------------------
// prep: xpad = fp16(batch) with zero guard rows at t=-1 and t=T; also zero
// h1pad guard rows (ws is re-poisoned before every launch).
__global__ __launch_bounds__(256) void prep_pad(const float* __restrict__ batch,
                                                f16* __restrict__ xpad,
                                                f16* __restrict__ h1pad) {
    int row = blockIdx.x * 4 + (threadIdx.x >> 6);   // 0 .. B_*TP_-1
    int lane = threadIdx.x & 63;
    int b = row / TP_, tt = row % TP_;
    size_t dsto = (size_t)row * C_ + lane * 8;
    if (tt == 0 || tt == TP_ - 1) {
        f16x8 z = {};
        *(f16x8*)(xpad + dsto) = z;
        *(f16x8*)(h1pad + dsto) = z;
    } else {
        const float* src = batch + ((size_t)(b * T_ + tt - 1)) * C_ + lane * 8;
        float4 v0 = ((const float4*)src)[0];
        float4 v1 = ((const float4*)src)[1];
        f16x8 h;
        h[0] = (f16)v0.x; h[1] = (f16)v0.y; h[2] = (f16)v0.z; h[3] = (f16)v0.w;
        h[4] = (f16)v1.x; h[5] = (f16)v1.y; h[6] = (f16)v1.z; h[7] = (f16)v1.w;
        *(f16x8*)(xpad + dsto) = h;
    }
}

// ---------------------------------------------------------------------------
// prep weights: wt[o][tap*512+i] = w[o][i][tap], fp16.  w is [512][512][3].
__global__ __launch_bounds__(256) void prep_w(const float* __restrict__ w1,
                                              const float* __restrict__ w2,
                                              f16* __restrict__ w1t,
                                              f16* __restrict__ w2t) {
    int o = blockIdx.x;
    const float* w = blockIdx.y ? w2 : w1;
    f16* wt = blockIdx.y ? w2t : w1t;
    for (int j = threadIdx.x; j < KDIM; j += 256) {
        int tap = j >> 9, i = j & 511;
        wt[(size_t)o * KDIM + j] = (f16)w[(size_t)o * KDIM + i * 3 + tap];
    }
}

// ---------------------------------------------------------------------------
// per-batch duration scan + direct inverse-map scatter (searchsorted inverse).
__global__ __launch_bounds__(1024) void scan_kernel(const int* __restrict__ dur,
                                                    const int* __restrict__ tlen,
                                                    int* __restrict__ idxarr,
                                                    int* __restrict__ total,
                                                    float* __restrict__ mel_out) {
    int b = blockIdx.x, t = threadIdx.x;
    __shared__ int sd[1024];
    __shared__ int sv[1024];
    int L = tlen[b];
    int valid = (t < L) ? 1 : 0;
    int d = valid ? dur[b * T_ + t] : 0;
    sd[t] = d; sv[t] = valid;
    __syncthreads();
    for (int off = 1; off < 1024; off <<= 1) {
        int x = 0, y = 0;
        if (t >= off) { x = sd[t - off]; y = sv[t - off]; }
        __syncthreads();
        sd[t] += x; sv[t] += y;
        __syncthreads();
    }
    int totd = sd[1023];
    int cur  = (totd == 0) ? sv[t] : sd[t];
    int prev = (t == 0) ? 0 : ((totd == 0) ? sv[t - 1] : sd[t - 1]);
    for (int f = prev; f < cur; f++) idxarr[b * LMAX_ + f] = t;
    if (t == 1023) {
        int tt = (totd == 0) ? sv[1023] : totd;
        total[b] = tt;
        mel_out[b] = (float)tt;
    }
}

// ---------------------------------------------------------------------------
// implicit-GEMM conv fused with LayerNorm epilogue.
// BM=64 x BN=512 block, 4 waves, wave tile 64x128 (4x8 frags of 16x16x32).
// Main loop per-wave is identical to R7 (24 ds_read_b128 : 64 MFMA / k-iter).
// EPI=0: y=relu(A@Bw^T+bias); LN(y)*g+beta -> f16 hpad (shifted +1 row).
// EPI=1: same LN, then dot with lw -> pred[m] (masked by tlen); no Y write.
// XOR granule swizzle: LDS[r][s] holds global granule s^(r&7).
template<int EPI>
__global__ __launch_bounds__(256, 2) void gemm_fused(const f16* __restrict__ A,
                                                     const f16* __restrict__ Bw,
                                                     const float* __restrict__ bias,
                                                     const float* __restrict__ g,
                                                     const float* __restrict__ be,
                                                     const float* __restrict__ lw,
                                                     const float* __restrict__ lb,
                                                     const int* __restrict__ tlen,
                                                     f16* __restrict__ hpad,
                                                     float* __restrict__ pred) {
    __shared__ f16 As[64 * 64];     //  8 KB
    __shared__ f16 Bs[512 * 64];    // 64 KB
    __shared__ float red[4][64][2]; //  2 KB cross-wave reduction scratch
    const int tid = threadIdx.x;
    const int lane = tid & 63;
    const int w = tid >> 6;        // 0..3
    const int m0 = blockIdx.x * 64;
    const int arow0 = (m0 >> 10) * TP_ + (m0 & 1023);
    const int wn = w * 128;        // wave's N offset (wave grid 1M x 4N)

    f32x4 acc[4][8];
#pragma unroll
    for (int i = 0; i < 4; i++)
#pragma unroll
        for (int j = 0; j < 8; j++) acc[i][j] = (f32x4){0.f, 0.f, 0.f, 0.f};

    const int lrow = lane >> 3;                  // 0..7
    const int gran = (lane & 7) ^ lrow;          // swizzled source granule
    const f16* aB = A + (size_t)(arow0 + lrow) * C_ + gran * 8;
    const f16* bB = Bw + (size_t)lrow * KDIM + gran * 8;

    for (int kk = 0; kk < KDIM; kk += 64) {
        __syncthreads();
#pragma unroll
        for (int i = 0; i < 2; i++) {           // A: 8 wave-loads / 4 waves
            const int rb = (w + i * 4) * 8;
            __builtin_amdgcn_global_load_lds(AS1C(aB + (size_t)rb * C_ + kk),
                                             AS3(&As[rb * 64]), 16, 0, 0);
        }
#pragma unroll
        for (int j = 0; j < 16; j++) {          // B: 64 wave-loads / 4 waves
            const int rb = (w + j * 4) * 8;
            __builtin_amdgcn_global_load_lds(AS1C(bB + (size_t)rb * KDIM + kk),
                                             AS3(&Bs[rb * 64]), 16, 0, 0);
        }
        __syncthreads();   // drains vmcnt -> LDS tiles complete
#pragma unroll
        for (int ks = 0; ks < 2; ks++) {
            const int sl = ((ks << 2) + (lane >> 4)) ^ (lane & 7);
            f16x8 af[4], bf[8];
#pragma unroll
            for (int mi = 0; mi < 4; mi++)
                af[mi] = *(const f16x8*)&As[(mi * 16 + (lane & 15)) * 64 + sl * 8];
#pragma unroll
            for (int ni = 0; ni < 8; ni++)
                bf[ni] = *(const f16x8*)&Bs[(wn + ni * 16 + (lane & 15)) * 64 + sl * 8];
#pragma unroll
            for (int mi = 0; mi < 4; mi++)
#pragma unroll
                for (int ni = 0; ni < 8; ni++)
                    acc[mi][ni] = __builtin_amdgcn_mfma_f32_16x16x32_f16(
                        af[mi], bf[ni], acc[mi][ni], 0, 0, 0);
        }
    }

    // ---------------- fused epilogue ----------------
    const int col = lane & 15;
    const int row4 = (lane >> 4) * 4;

    // bias + relu in-register, accumulate per-row sum/sumsq
    float bn[8];
#pragma unroll
    for (int ni = 0; ni < 8; ni++) bn[ni] = bias[wn + ni * 16 + col];
    float s_[4][4], q_[4][4];
#pragma unroll
    for (int mi = 0; mi < 4; mi++)
#pragma unroll
        for (int r = 0; r < 4; r++) { s_[mi][r] = 0.f; q_[mi][r] = 0.f; }
#pragma unroll
    for (int mi = 0; mi < 4; mi++)
#pragma unroll
        for (int ni = 0; ni < 8; ni++)
#pragma unroll
            for (int r = 0; r < 4; r++) {
                float v = acc[mi][ni][r] + bn[ni];
                v = v > 0.f ? v : 0.f;
                acc[mi][ni][r] = v;
                s_[mi][r] += v;
                q_[mi][r] += v * v;
            }
    // reduce across the 16 col-lanes (same rows live at same lane>>4)
#pragma unroll
    for (int m = 8; m; m >>= 1)
#pragma unroll
        for (int mi = 0; mi < 4; mi++)
#pragma unroll
            for (int r = 0; r < 4; r++) {
                s_[mi][r] += __shfl_xor(s_[mi][r], m, 64);
                q_[mi][r] += __shfl_xor(q_[mi][r], m, 64);
            }
    // cross-wave reduce via LDS (4 N-waves hold disjoint col ranges)
    if (col == 0) {
#pragma unroll
        for (int mi = 0; mi < 4; mi++)
#pragma unroll
            for (int r = 0; r < 4; r++) {
                int row = mi * 16 + row4 + r;
                red[w][row][0] = s_[mi][r];
                red[w][row][1] = q_[mi][r];
            }
    }
    __syncthreads();
    float mu_[4][4], rs_[4][4];
#pragma unroll
    for (int mi = 0; mi < 4; mi++)
#pragma unroll
        for (int r = 0; r < 4; r++) {
            int row = mi * 16 + row4 + r;
            float S = red[0][row][0] + red[1][row][0] + red[2][row][0] + red[3][row][0];
            float Q = red[0][row][1] + red[1][row][1] + red[2][row][1] + red[3][row][1];
            float mu = S * (1.f / 512.f);
            float x = Q * (1.f / 512.f) - mu * mu + 1e-5f;
            float rs = rsqrtf(x);
            rs = rs * (1.5f - 0.5f * x * rs * rs);   // Newton refine
            mu_[mi][r] = mu; rs_[mi][r] = rs;
        }

    if (EPI == 0) {
        // LN -> f16 hpad at (b, t+1)
        const int bb = m0 >> 10, t0 = m0 & 1023;
        f16* hbase = hpad + ((size_t)(bb * TP_ + t0 + 1)) * C_;
#pragma unroll
        for (int ni = 0; ni < 8; ni++) {
            int n = wn + ni * 16 + col;
            float gv = g[n], ev = be[n];
#pragma unroll
            for (int mi = 0; mi < 4; mi++)
#pragma unroll
                for (int r = 0; r < 4; r++) {
                    int lm = mi * 16 + row4 + r;
                    float v = (acc[mi][ni][r] - mu_[mi][r]) * rs_[mi][r] * gv + ev;
                    hbase[(size_t)lm * C_ + n] = (f16)v;
                }
        }
    } else {
        // LN + Linear head -> pred[m], masked by token length
        float p_[4][4];
#pragma unroll
        for (int mi = 0; mi < 4; mi++)
#pragma unroll
            for (int r = 0; r < 4; r++) p_[mi][r] = 0.f;
#pragma unroll
        for (int ni = 0; ni < 8; ni++) {
            int n = wn + ni * 16 + col;
            float gv = g[n], ev = be[n], wv = lw[n];
#pragma unroll
            for (int mi = 0; mi < 4; mi++)
#pragma unroll
                for (int r = 0; r < 4; r++)
                    p_[mi][r] += ((acc[mi][ni][r] - mu_[mi][r]) * rs_[mi][r] * gv + ev) * wv;
        }
#pragma unroll
        for (int m = 8; m; m >>= 1)
#pragma unroll
            for (int mi = 0; mi < 4; mi++)
#pragma unroll
                for (int r = 0; r < 4; r++)
                    p_[mi][r] += __shfl_xor(p_[mi][r], m, 64);
        __syncthreads();   // all red[] stat reads complete before reuse
        if (col == 0) {
#pragma unroll
            for (int mi = 0; mi < 4; mi++)
#pragma unroll
                for (int r = 0; r < 4; r++)
                    red[w][mi * 16 + row4 + r][0] = p_[mi][r];
        }
        __syncthreads();
        if (tid < 64) {
            int m = m0 + tid;
            float p = red[0][tid][0] + red[1][tid][0] + red[2][tid][0] + red[3][tid][0];
            int bb = m >> 10, t = m & 1023;
            pred[m] = (t < tlen[bb]) ? (p + lb[0]) : 0.f;
        }
    }
}

// ---------------------------------------------------------------------------
// regulate gather: wave per output frame row; precomputed idx (no search).
__global__ __launch_bounds__(256) void gather_kernel(const float* __restrict__ batch,
                                                     const int* __restrict__ idxarr,
                                                     const int* __restrict__ total,
                                                     float* __restrict__ out) {
    int gw = blockIdx.x * 4 + (threadIdx.x >> 6);  // 0 .. B_*LMAX_-1
    int lane = threadIdx.x & 63;
    int b = gw >> 12;
    int l = gw & (LMAX_ - 1);
    int tot = total[b];
    float4* dst = (float4*)(out + ((size_t)b * LMAX_ + l) * C_);
    if (l < tot) {
        int idx = idxarr[gw];
        const float4* src = (const float4*)(batch + ((size_t)b * T_ + idx) * C_);
        dst[lane] = src[lane];
        dst[lane + 64] = src[lane + 64];
    } else {
        float4 z = {0.f, 0.f, 0.f, 0.f};
        dst[lane] = z;
        dst[lane + 64] = z;
    }
}

// ---------------------------------------------------------------------------
extern "C" void kernel_launch(void* const* d_in, const int* in_sizes, int n_in,
                              void* d_out, int out_size, void* d_ws, size_t ws_size,
                              hipStream_t stream) {
    const float* batch = (const float*)d_in[0];
    const int* tlen    = (const int*)d_in[1];
    const int* durs    = (const int*)d_in[3];
    const float* w1  = (const float*)d_in[4];
    const float* b1  = (const float*)d_in[5];
    const float* g1  = (const float*)d_in[6];
    const float* be1 = (const float*)d_in[7];
    const float* w2  = (const float*)d_in[8];
    const float* b2  = (const float*)d_in[9];
    const float* g2  = (const float*)d_in[10];
    const float* be2 = (const float*)d_in[11];
    const float* lw  = (const float*)d_in[12];
    const float* lb  = (const float*)d_in[13];

    float* out      = (float*)d_out;
    float* mel_out  = out + (size_t)B_ * LMAX_ * C_;
    float* pred_out = mel_out + B_;

    char* ws    = (char*)d_ws;
    f16* xpad   = (f16*)(ws + XPAD_OFF);
    f16* h1pad  = (f16*)(ws + H1PAD_OFF);
    f16* w1t    = (f16*)(ws + W1T_OFF);
    f16* w2t    = (f16*)(ws + W2T_OFF);
    int* tot    = (int*)(ws + TOT_OFF);
    int* idxarr = (int*)(ws + IDX_OFF);

    prep_pad<<<B_ * TP_ / 4, 256, 0, stream>>>(batch, xpad, h1pad);
    prep_w<<<dim3(512, 2), 256, 0, stream>>>(w1, w2, w1t, w2t);
    scan_kernel<<<B_, 1024, 0, stream>>>(durs, tlen, idxarr, tot, mel_out);
    gemm_fused<0><<<512, 256, 0, stream>>>(xpad, w1t, b1, g1, be1,
                                           nullptr, nullptr, nullptr, h1pad, nullptr);
    gemm_fused<1><<<512, 256, 0, stream>>>(h1pad, w2t, b2, g2, be2,
                                           lw, lb, tlen, nullptr, pred_out);
    gather_kernel<<<B_ * LMAX_ / 4, 256, 0, stream>>>(batch, idxarr, tot, out);
}